// Round 5
// baseline (111.970 us; speedup 1.0000x reference)
//
#include <hip/hip_runtime.h>

#define BD 4096   // rows
#define CD 256    // codes
#define DD 128    // dim
#define RB 4      // rows per block -> grid 1024 (~4 blocks/CU by LDS)
#define CW 16     // codes per wave-private LDS tile
#define NTW 4     // tiles per wave: 4 waves x 4 tiles x 16 codes = 256
#define SF 132    // LDS row stride in floats (33 quads; quad-stride 33 -> bank spread)

// NOTE: no 2nd __launch_bounds__ arg — R4 showed (256,4) => VGPR=32 + massive
// scratch spills (72 MB writes) on this toolchain.
__global__ __launch_bounds__(256) void rq_fused(
    const float* __restrict__ x,
    const float* __restrict__ pq,
    const float* __restrict__ codes,
    float* __restrict__ out)   // [quantized BD*DD | indices BD | loss 1]
{
    __shared__ float xc_s[RB * SF];            // rotated rows
    __shared__ float code_s[4 * CW * SF];      // 4 wave-private 16-code regions
    __shared__ float row_c[RB], row_s[RB], row_invn[RB];
    __shared__ int   row_idx[RB];
    __shared__ float red_v[RB * 4];            // [row][wave]
    __shared__ int   red_i[RB * 4];
    __shared__ float loss_s[RB];

    const int tid  = threadIdx.x;
    const int wv   = tid >> 6;
    const int lane = tid & 63;
    const int row0 = blockIdx.x * RB;
    const float INV_SQRT_D = 0.088388347648318447f;  // 1/sqrt(128)

    // ---- prefetch this wave's tile 0 (tile index = wv): 512 float4, 8/lane ----
    const float4* csrc = (const float4*)codes;
    float4 pf[8];
    #pragma unroll
    for (int k = 0; k < 8; ++k)
        pf[k] = csrc[(size_t)wv * (CW * DD / 4) + k * 64 + lane];

    // ---------- Phase A: per-row rotation  xc = R^T x (rank-2 form) ----------
    // wave wv handles row wv; each lane holds 2 elements (float2).
    {
        const int r = wv;
        const size_t grow = (size_t)(row0 + r);
        const float2 xv = ((const float2*)(x  + grow * DD))[lane];
        const float2 pv = ((const float2*)(pq + grow * DD))[lane];
        float s0 = pv.x * pv.x + pv.y * pv.y;   // ||pq||^2
        float s1 = pv.x + pv.y;                 // sum pq
        float s2 = xv.x + xv.y;                 // sum x
        float s3 = pv.x * xv.x + pv.y * xv.y;   // pq . x
        #pragma unroll
        for (int m = 32; m > 0; m >>= 1) {
            s0 += __shfl_xor(s0, m);
            s1 += __shfl_xor(s1, m);
            s2 += __shfl_xor(s2, m);
            s3 += __shfl_xor(s3, m);
        }
        const float invn = 1.0f / fmaxf(sqrtf(s0), 1e-6f);  // u = pq * invn
        const float b = s2 * INV_SQRT_D;                    // v.x
        const float a = s3 * invn;                          // u.x
        const float c = s1 * invn * INV_SQRT_D;             // u.v
        const float s = 1.0f / (1.0f + c + 1e-6f);
        // R^T x = x + u*(-b + s(cb - a)) + v*(a + s(ca - b))
        const float au = -b + s * (c * b - a);
        const float av =  a + s * (c * a - b);
        xc_s[r * SF + 2 * lane]     = xv.x + au * (pv.x * invn) + av * INV_SQRT_D;
        xc_s[r * SF + 2 * lane + 1] = xv.y + au * (pv.y * invn) + av * INV_SQRT_D;
        if (lane == 0) { row_c[r] = c; row_s[r] = s; row_invn[r] = invn; }
    }
    __syncthreads();   // xc_s (all 4 rows) visible to all waves

    // ---------- Phase B: distances + argmin (NO barriers; waves independent) ----
    // thread = 4 rows x 1 code x quarter-D. lane -> code cit (0..15), quarter qd.
    const int cit = lane & 15;
    const int qd  = lane >> 4;
    float bv0 = 3.4e38f, bv1 = 3.4e38f, bv2 = 3.4e38f, bv3 = 3.4e38f;
    int   bi0 = 0, bi1 = 0, bi2 = 0, bi3 = 0;
    float* cbase = code_s + wv * (CW * SF);

    for (int s = 0; s < NTW; ++s) {
        // stage prefetched tile into this wave's private region (in-order DS ops)
        #pragma unroll
        for (int k = 0; k < 8; ++k) {
            const int f = k * 64 + lane;           // [0,512)
            *(float4*)(cbase + (f >> 5) * SF + (f & 31) * 4) = pf[k];
        }
        if (s + 1 < NTW) {                          // prefetch next tile (L2-hot)
            const size_t t = (size_t)(wv + 4 * (s + 1));
            #pragma unroll
            for (int k = 0; k < 8; ++k)
                pf[k] = csrc[t * (CW * DD / 4) + k * 64 + lane];
        }

        const float* cp = cbase + cit * SF + qd * 32;   // this thread's 32-float quarter
        const float* x0 = xc_s + 0 * SF + qd * 32;
        const float* x1 = xc_s + 1 * SF + qd * 32;
        const float* x2 = xc_s + 2 * SF + qd * 32;
        const float* x3 = xc_s + 3 * SF + qd * 32;
        float a0 = 0.f, a1 = 0.f, a2 = 0.f, a3 = 0.f;
        #pragma unroll
        for (int i = 0; i < 8; ++i) {
            const int d4 = ((i + qd) & 7) * 4;     // rotate start by quarter: bank spread
            const float4 cv = *(const float4*)(cp + d4);
            const float4 v0 = *(const float4*)(x0 + d4);
            const float4 v1 = *(const float4*)(x1 + d4);
            const float4 v2 = *(const float4*)(x2 + d4);
            const float4 v3 = *(const float4*)(x3 + d4);
            float dx;
            dx = v0.x - cv.x; a0 = fmaf(dx, dx, a0);
            dx = v0.y - cv.y; a0 = fmaf(dx, dx, a0);
            dx = v0.z - cv.z; a0 = fmaf(dx, dx, a0);
            dx = v0.w - cv.w; a0 = fmaf(dx, dx, a0);
            dx = v1.x - cv.x; a1 = fmaf(dx, dx, a1);
            dx = v1.y - cv.y; a1 = fmaf(dx, dx, a1);
            dx = v1.z - cv.z; a1 = fmaf(dx, dx, a1);
            dx = v1.w - cv.w; a1 = fmaf(dx, dx, a1);
            dx = v2.x - cv.x; a2 = fmaf(dx, dx, a2);
            dx = v2.y - cv.y; a2 = fmaf(dx, dx, a2);
            dx = v2.z - cv.z; a2 = fmaf(dx, dx, a2);
            dx = v2.w - cv.w; a2 = fmaf(dx, dx, a2);
            dx = v3.x - cv.x; a3 = fmaf(dx, dx, a3);
            dx = v3.y - cv.y; a3 = fmaf(dx, dx, a3);
            dx = v3.z - cv.z; a3 = fmaf(dx, dx, a3);
            dx = v3.w - cv.w; a3 = fmaf(dx, dx, a3);
        }
        // combine the 4 quarter-sums (lanes qd=0..3 of same cit) -> full distances
        a0 += __shfl_xor(a0, 16); a0 += __shfl_xor(a0, 32);
        a1 += __shfl_xor(a1, 16); a1 += __shfl_xor(a1, 32);
        a2 += __shfl_xor(a2, 16); a2 += __shfl_xor(a2, 32);
        a3 += __shfl_xor(a3, 16); a3 += __shfl_xor(a3, 32);
        const int ci = (wv + 4 * s) * CW + cit;    // ascending in s -> first-min kept
        if (a0 < bv0) { bv0 = a0; bi0 = ci; }
        if (a1 < bv1) { bv1 = a1; bi1 = ci; }
        if (a2 < bv2) { bv2 = a2; bi2 = ci; }
        if (a3 < bv3) { bv3 = a3; bi3 = ci; }
    }

    // wave-level argmin over 64 lanes (qd-duplicates are identical; tie-break on index)
    #pragma unroll
    for (int m = 1; m < 64; m <<= 1) {
        float ov; int oi;
        ov = __shfl_xor(bv0, m); oi = __shfl_xor(bi0, m);
        if (ov < bv0 || (ov == bv0 && oi < bi0)) { bv0 = ov; bi0 = oi; }
        ov = __shfl_xor(bv1, m); oi = __shfl_xor(bi1, m);
        if (ov < bv1 || (ov == bv1 && oi < bi1)) { bv1 = ov; bi1 = oi; }
        ov = __shfl_xor(bv2, m); oi = __shfl_xor(bi2, m);
        if (ov < bv2 || (ov == bv2 && oi < bi2)) { bv2 = ov; bi2 = oi; }
        ov = __shfl_xor(bv3, m); oi = __shfl_xor(bi3, m);
        if (ov < bv3 || (ov == bv3 && oi < bi3)) { bv3 = ov; bi3 = oi; }
    }
    if (lane == 0) {
        red_v[0 * 4 + wv] = bv0; red_i[0 * 4 + wv] = bi0;
        red_v[1 * 4 + wv] = bv1; red_i[1 * 4 + wv] = bi1;
        red_v[2 * 4 + wv] = bv2; red_i[2 * 4 + wv] = bi2;
        red_v[3 * 4 + wv] = bv3; red_i[3 * 4 + wv] = bi3;
    }
    __syncthreads();
    if (tid < RB) {   // thread r finalizes row r across the 4 waves
        float bv = red_v[tid * 4];
        int   bi = red_i[tid * 4];
        #pragma unroll
        for (int w = 1; w < 4; ++w) {
            const float ov = red_v[tid * 4 + w];
            const int   oi = red_i[tid * 4 + w];
            if (ov < bv || (ov == bv && oi < bi)) { bv = ov; bi = oi; }
        }
        row_idx[tid] = bi;
        out[(size_t)BD * DD + row0 + tid] = (float)bi;
    }
    __syncthreads();

    // ---------- Phase C: quantized = R * codes[idx] (rank-2), + loss ----------
    // wave wv = row wv; each lane handles 2 elements (float2)
    {
        const int r = wv;
        const int qi = row_idx[r];
        const float invn = row_invn[r];
        const float c = row_c[r];
        const float s = row_s[r];
        const size_t grow = (size_t)(row0 + r);
        const float2 q = ((const float2*)(codes + (size_t)qi * DD))[lane];
        const float2 p = ((const float2*)(pq + grow * DD))[lane];
        float pd = p.x * q.x + p.y * q.y;
        float ws = q.x + q.y;
        #pragma unroll
        for (int m = 32; m > 0; m >>= 1) {
            pd += __shfl_xor(pd, m);
            ws += __shfl_xor(ws, m);
        }
        const float pp = pd * invn;          // u . q
        const float w  = ws * INV_SQRT_D;    // v . q
        // R q = q + u*(w + s(cw - p)) + v*(-p + s(cp - w))
        const float bu =  w + s * (c * w - pp);
        const float bvv = -pp + s * (c * pp - w);
        float2 o;
        o.x = q.x + bu * (p.x * invn) + bvv * INV_SQRT_D;
        o.y = q.y + bu * (p.y * invn) + bvv * INV_SQRT_D;
        ((float2*)(out + grow * DD))[lane] = o;

        const float2 xv = ((const float2*)(x + grow * DD))[lane];
        float dx = xv.x - o.x;
        float ls = dx * dx;
        dx = xv.y - o.y;
        ls = fmaf(dx, dx, ls);
        #pragma unroll
        for (int m = 32; m > 0; m >>= 1) ls += __shfl_xor(ls, m);
        if (lane == 0) loss_s[r] = ls;
    }
    __syncthreads();
    if (tid == 0) {
        const float tot = loss_s[0] + loss_s[1] + loss_s[2] + loss_s[3];
        // loss = loss_commit + 0.25*loss_codebook = 1.25 * mean_b ||x - q||^2
        atomicAdd(out + (size_t)BD * DD + BD, tot * (1.25f / (float)BD));
    }
}

extern "C" void kernel_launch(void* const* d_in, const int* in_sizes, int n_in,
                              void* d_out, int out_size, void* d_ws, size_t ws_size,
                              hipStream_t stream) {
    const float* xin   = (const float*)d_in[0];
    const float* prevq = (const float*)d_in[1];
    const float* codes = (const float*)d_in[2];
    float* out = (float*)d_out;
    // zero the loss accumulator slot (harness poisons d_out with 0xAA)
    hipMemsetAsync((void*)(out + (size_t)BD * DD + BD), 0, sizeof(float), stream);
    rq_fused<<<BD / RB, 256, 0, stream>>>(xin, prevq, codes, out);
}

// Round 6
// 80.987 us; speedup vs baseline: 1.3826x; 1.3826x over previous
//
#include <hip/hip_runtime.h>

#define BD 4096   // rows
#define CD 256    // codes
#define DD 128    // dim
#define RB 16     // rows per block -> grid 256 = 1 block/CU (LDS-resident codebook)
#define SF 132    // padded LDS row stride in floats (33 quads -> conflict-free bank spread)

// NOTE (R4/R5 lesson): no 2nd __launch_bounds__ arg, and NO register-carried
// prefetch arrays across staging phases — both caused ~70 MB scratch spills.
__global__ __launch_bounds__(256) void rq_fused(
    const float* __restrict__ x,
    const float* __restrict__ pq,
    const float* __restrict__ codes,
    float* __restrict__ out)   // [quantized BD*DD | indices BD | loss 1]
{
    __shared__ float code_s[CD * SF];          // 135168 B: full padded codebook
    __shared__ float xc_s[RB * SF];            // 8448 B: rotated rows
    __shared__ float row_c[RB], row_s[RB], row_invn[RB];
    __shared__ int   row_idx[RB];
    __shared__ float red_v[RB * 2];            // [row][code-half wave]
    __shared__ int   red_i[RB * 2];
    __shared__ float loss_s[RB];

    const int tid  = threadIdx.x;
    const int wv   = tid >> 6;
    const int lane = tid & 63;
    const int row0 = blockIdx.x * RB;
    const float INV_SQRT_D = 0.088388347648318447f;  // 1/sqrt(128)

    // ---- stage full codebook to LDS, batched x4, load->store immediately ----
    {
        const float4* src = (const float4*)codes;   // 8192 float4 total
        for (int k = 0; k < 32; k += 4) {           // 32 float4 per thread
            const float4 t0 = src[(k + 0) * 256 + tid];
            const float4 t1 = src[(k + 1) * 256 + tid];
            const float4 t2 = src[(k + 2) * 256 + tid];
            const float4 t3 = src[(k + 3) * 256 + tid];
            int f;
            f = (k + 0) * 256 + tid; *(float4*)(code_s + (f >> 5) * SF + (f & 31) * 4) = t0;
            f = (k + 1) * 256 + tid; *(float4*)(code_s + (f >> 5) * SF + (f & 31) * 4) = t1;
            f = (k + 2) * 256 + tid; *(float4*)(code_s + (f >> 5) * SF + (f & 31) * 4) = t2;
            f = (k + 3) * 256 + tid; *(float4*)(code_s + (f >> 5) * SF + (f & 31) * 4) = t3;
        }
    }

    // ---------- Phase A: per-row rotation  xc = R^T x (rank-2 form) ----------
    // wave wv handles rows wv*4 .. wv*4+3; each lane holds 2 elements (float2).
    #pragma unroll
    for (int rr = 0; rr < 4; ++rr) {
        const int r = wv * 4 + rr;
        const size_t grow = (size_t)(row0 + r);
        const float2 xv = ((const float2*)(x  + grow * DD))[lane];
        const float2 pv = ((const float2*)(pq + grow * DD))[lane];
        float s0 = pv.x * pv.x + pv.y * pv.y;   // ||pq||^2
        float s1 = pv.x + pv.y;                 // sum pq
        float s2 = xv.x + xv.y;                 // sum x
        float s3 = pv.x * xv.x + pv.y * xv.y;   // pq . x
        #pragma unroll
        for (int m = 32; m > 0; m >>= 1) {
            s0 += __shfl_xor(s0, m);
            s1 += __shfl_xor(s1, m);
            s2 += __shfl_xor(s2, m);
            s3 += __shfl_xor(s3, m);
        }
        const float invn = 1.0f / fmaxf(sqrtf(s0), 1e-6f);  // u = pq * invn
        const float b = s2 * INV_SQRT_D;                    // v.x
        const float a = s3 * invn;                          // u.x
        const float c = s1 * invn * INV_SQRT_D;             // u.v
        const float s = 1.0f / (1.0f + c + 1e-6f);
        // R^T x = x + u*(-b + s(cb - a)) + v*(a + s(ca - b))
        const float au = -b + s * (c * b - a);
        const float av =  a + s * (c * a - b);
        xc_s[r * SF + 2 * lane]     = xv.x + au * (pv.x * invn) + av * INV_SQRT_D;
        xc_s[r * SF + 2 * lane + 1] = xv.y + au * (pv.y * invn) + av * INV_SQRT_D;
        if (lane == 0) { row_c[r] = c; row_s[r] = s; row_invn[r] = invn; }
    }
    __syncthreads();   // code_s + xc_s ready

    // ---------- Phase B: distances (no barriers, no register carry) ----------
    // wave -> 8 rows x 128 codes; thread -> codes (cbase+lane, cbase+64+lane) x 8 rows
    const int rbase = (wv >> 1) * 8;           // rows 0-7 (waves 0,1) / 8-15 (waves 2,3)
    const int cbase = (wv & 1) * 128;          // codes 0-127 / 128-255
    const float* cp0 = code_s + (cbase + lane) * SF;
    const float* cp1 = cp0 + 64 * SF;
    const float* xb  = xc_s + rbase * SF;
    float acc[16];
    #pragma unroll
    for (int j = 0; j < 16; ++j) acc[j] = 0.f;

    #pragma unroll 2
    for (int i = 0; i < 32; ++i) {
        const float4 q0 = *(const float4*)(cp0 + i * 4);   // quad (lane+i)&31: 2-way, free
        const float4 q1 = *(const float4*)(cp1 + i * 4);
        #pragma unroll
        for (int rr = 0; rr < 8; ++rr) {
            const float4 xv = *(const float4*)(xb + rr * SF + i * 4);  // uniform: broadcast
            float dx;
            dx = xv.x - q0.x; acc[rr * 2]     = fmaf(dx, dx, acc[rr * 2]);
            dx = xv.y - q0.y; acc[rr * 2]     = fmaf(dx, dx, acc[rr * 2]);
            dx = xv.z - q0.z; acc[rr * 2]     = fmaf(dx, dx, acc[rr * 2]);
            dx = xv.w - q0.w; acc[rr * 2]     = fmaf(dx, dx, acc[rr * 2]);
            dx = xv.x - q1.x; acc[rr * 2 + 1] = fmaf(dx, dx, acc[rr * 2 + 1]);
            dx = xv.y - q1.y; acc[rr * 2 + 1] = fmaf(dx, dx, acc[rr * 2 + 1]);
            dx = xv.z - q1.z; acc[rr * 2 + 1] = fmaf(dx, dx, acc[rr * 2 + 1]);
            dx = xv.w - q1.w; acc[rr * 2 + 1] = fmaf(dx, dx, acc[rr * 2 + 1]);
        }
    }

    // per-row select between this thread's 2 codes (lower index wins ties)
    float bv[8]; int bi[8];
    #pragma unroll
    for (int rr = 0; rr < 8; ++rr) {
        const float v0 = acc[rr * 2], v1 = acc[rr * 2 + 1];
        if (v1 < v0) { bv[rr] = v1; bi[rr] = cbase + 64 + lane; }
        else         { bv[rr] = v0; bi[rr] = cbase + lane; }
    }
    // wave argmin over 64 lanes (distinct codes; tie-break on index)
    #pragma unroll
    for (int m = 1; m < 64; m <<= 1) {
        #pragma unroll
        for (int rr = 0; rr < 8; ++rr) {
            const float ov = __shfl_xor(bv[rr], m);
            const int   oi = __shfl_xor(bi[rr], m);
            if (ov < bv[rr] || (ov == bv[rr] && oi < bi[rr])) { bv[rr] = ov; bi[rr] = oi; }
        }
    }
    if (lane == 0) {
        #pragma unroll
        for (int rr = 0; rr < 8; ++rr) {
            red_v[(rbase + rr) * 2 + (wv & 1)] = bv[rr];
            red_i[(rbase + rr) * 2 + (wv & 1)] = bi[rr];
        }
    }
    __syncthreads();
    if (tid < RB) {   // merge the two code-half waves per row
        float v0 = red_v[tid * 2]; int i0 = red_i[tid * 2];
        const float v1 = red_v[tid * 2 + 1]; const int i1 = red_i[tid * 2 + 1];
        if (v1 < v0 || (v1 == v0 && i1 < i0)) { v0 = v1; i0 = i1; }
        row_idx[tid] = i0;
        out[(size_t)BD * DD + row0 + tid] = (float)i0;
    }
    __syncthreads();

    // ---------- Phase C: quantized = R * codes[idx] (rank-2), + loss ----------
    // wave wv -> rows wv*4 .. wv*4+3; lane holds 2 elements; code row from LDS.
    #pragma unroll
    for (int rr = 0; rr < 4; ++rr) {
        const int r = wv * 4 + rr;
        const int qi = row_idx[r];
        const float invn = row_invn[r];
        const float c = row_c[r];
        const float s = row_s[r];
        const size_t grow = (size_t)(row0 + r);
        const float2 q = ((const float2*)(code_s + qi * SF))[lane];
        const float2 p = ((const float2*)(pq + grow * DD))[lane];
        float pd = p.x * q.x + p.y * q.y;
        float ws = q.x + q.y;
        #pragma unroll
        for (int m = 32; m > 0; m >>= 1) {
            pd += __shfl_xor(pd, m);
            ws += __shfl_xor(ws, m);
        }
        const float pp = pd * invn;          // u . q
        const float w  = ws * INV_SQRT_D;    // v . q
        // R q = q + u*(w + s(cw - p)) + v*(-p + s(cp - w))
        const float bu  =  w + s * (c * w - pp);
        const float bvv = -pp + s * (c * pp - w);
        float2 o;
        o.x = q.x + bu * (p.x * invn) + bvv * INV_SQRT_D;
        o.y = q.y + bu * (p.y * invn) + bvv * INV_SQRT_D;
        ((float2*)(out + grow * DD))[lane] = o;

        const float2 xv = ((const float2*)(x + grow * DD))[lane];
        float dx = xv.x - o.x;
        float ls = dx * dx;
        dx = xv.y - o.y;
        ls = fmaf(dx, dx, ls);
        #pragma unroll
        for (int m = 32; m > 0; m >>= 1) ls += __shfl_xor(ls, m);
        if (lane == 0) loss_s[r] = ls;
    }
    __syncthreads();
    if (tid == 0) {
        float tot = 0.f;
        #pragma unroll
        for (int r = 0; r < RB; ++r) tot += loss_s[r];
        // loss = loss_commit + 0.25*loss_codebook = 1.25 * mean_b ||x - q||^2
        atomicAdd(out + (size_t)BD * DD + BD, tot * (1.25f / (float)BD));
    }
}

extern "C" void kernel_launch(void* const* d_in, const int* in_sizes, int n_in,
                              void* d_out, int out_size, void* d_ws, size_t ws_size,
                              hipStream_t stream) {
    const float* xin   = (const float*)d_in[0];
    const float* prevq = (const float*)d_in[1];
    const float* codes = (const float*)d_in[2];
    float* out = (float*)d_out;
    // zero the loss accumulator slot (harness poisons d_out with 0xAA)
    hipMemsetAsync((void*)(out + (size_t)BD * DD + BD), 0, sizeof(float), stream);
    rq_fused<<<BD / RB, 256, 0, stream>>>(xin, prevq, codes, out);
}

// Round 7
// 77.465 us; speedup vs baseline: 1.4454x; 1.0455x over previous
//
#include <hip/hip_runtime.h>

#define BD 4096   // rows
#define CD 256    // codes
#define DD 128    // dim
#define RB 16     // rows per block -> grid 256 = 1 block/CU (LDS-resident codebook)
#define TB 1024   // threads per block = 16 waves = 4 waves/SIMD (latency hiding)
#define SF 132    // padded LDS row stride in floats (33 quads -> conflict-free bank spread)

// Lessons kept: no 2nd __launch_bounds__ arg (R4: VGPR=32 + 72MB spills);
// no register-carried prefetch across staging (R5: spills); load->ds_write
// immediately in small batches (R2/R6: clean).
__global__ __launch_bounds__(TB) void rq_fused(
    const float* __restrict__ x,
    const float* __restrict__ pq,
    const float* __restrict__ codes,
    float* __restrict__ out)   // [quantized BD*DD | indices BD | loss 1]
{
    __shared__ float code_s[CD * SF];          // 135168 B: full padded codebook
    __shared__ float xc_s[RB * SF];            // 8448 B: rotated rows
    __shared__ float row_c[RB], row_s[RB], row_invn[RB];
    __shared__ int   row_idx[RB];
    __shared__ float red_v[RB * 4];            // [row][code-quarter]
    __shared__ int   red_i[RB * 4];
    __shared__ float loss_s[RB];

    const int tid  = threadIdx.x;
    const int wv   = tid >> 6;     // 0..15
    const int lane = tid & 63;
    const int row0 = blockIdx.x * RB;
    const float INV_SQRT_D = 0.088388347648318447f;  // 1/sqrt(128)

    // ---- stage full codebook to LDS: 8192 float4, 8 per thread, batch x4 ----
    {
        const float4* src = (const float4*)codes;
        #pragma unroll
        for (int k = 0; k < 8; k += 4) {
            const float4 t0 = src[(k + 0) * TB + tid];
            const float4 t1 = src[(k + 1) * TB + tid];
            const float4 t2 = src[(k + 2) * TB + tid];
            const float4 t3 = src[(k + 3) * TB + tid];
            int f;
            f = (k + 0) * TB + tid; *(float4*)(code_s + (f >> 5) * SF + (f & 31) * 4) = t0;
            f = (k + 1) * TB + tid; *(float4*)(code_s + (f >> 5) * SF + (f & 31) * 4) = t1;
            f = (k + 2) * TB + tid; *(float4*)(code_s + (f >> 5) * SF + (f & 31) * 4) = t2;
            f = (k + 3) * TB + tid; *(float4*)(code_s + (f >> 5) * SF + (f & 31) * 4) = t3;
        }
    }

    // ---------- Phase A: per-row rotation  xc = R^T x (rank-2 form) ----------
    // wave wv handles row wv; each lane holds 2 elements (float2).
    {
        const int r = wv;
        const size_t grow = (size_t)(row0 + r);
        const float2 xv = ((const float2*)(x  + grow * DD))[lane];
        const float2 pv = ((const float2*)(pq + grow * DD))[lane];
        float s0 = pv.x * pv.x + pv.y * pv.y;   // ||pq||^2
        float s1 = pv.x + pv.y;                 // sum pq
        float s2 = xv.x + xv.y;                 // sum x
        float s3 = pv.x * xv.x + pv.y * xv.y;   // pq . x
        #pragma unroll
        for (int m = 32; m > 0; m >>= 1) {
            s0 += __shfl_xor(s0, m);
            s1 += __shfl_xor(s1, m);
            s2 += __shfl_xor(s2, m);
            s3 += __shfl_xor(s3, m);
        }
        const float invn = 1.0f / fmaxf(sqrtf(s0), 1e-6f);  // u = pq * invn
        const float b = s2 * INV_SQRT_D;                    // v.x
        const float a = s3 * invn;                          // u.x
        const float c = s1 * invn * INV_SQRT_D;             // u.v
        const float s = 1.0f / (1.0f + c + 1e-6f);
        // R^T x = x + u*(-b + s(cb - a)) + v*(a + s(ca - b))
        const float au = -b + s * (c * b - a);
        const float av =  a + s * (c * a - b);
        xc_s[r * SF + 2 * lane]     = xv.x + au * (pv.x * invn) + av * INV_SQRT_D;
        xc_s[r * SF + 2 * lane + 1] = xv.y + au * (pv.y * invn) + av * INV_SQRT_D;
        if (lane == 0) { row_c[r] = c; row_s[r] = s; row_invn[r] = invn; }
    }
    __syncthreads();   // code_s + xc_s ready

    // ---------- Phase B: distances (no barriers, no register carry) ----------
    // wave -> 4 rows x 64 codes; thread -> 1 code (cq*64+lane) x 4 rows, full D
    const int rg = wv & 3;                     // row group: rows rg*4 .. rg*4+3
    const int cq = wv >> 2;                    // code quarter: codes cq*64 + lane
    const int ci = cq * 64 + lane;
    const float* cp = code_s + ci * SF;        // quad idx = ci*33 + i -> (lane+i)&31: free
    const float* xb = xc_s + (rg * 4) * SF;
    float a0 = 0.f, a1 = 0.f, a2 = 0.f, a3 = 0.f;

    #pragma unroll 4
    for (int i = 0; i < 32; ++i) {
        const float4 q  = *(const float4*)(cp + i * 4);
        const float4 v0 = *(const float4*)(xb + 0 * SF + i * 4);  // uniform: broadcast
        const float4 v1 = *(const float4*)(xb + 1 * SF + i * 4);
        const float4 v2 = *(const float4*)(xb + 2 * SF + i * 4);
        const float4 v3 = *(const float4*)(xb + 3 * SF + i * 4);
        float dx;
        dx = v0.x - q.x; a0 = fmaf(dx, dx, a0);
        dx = v0.y - q.y; a0 = fmaf(dx, dx, a0);
        dx = v0.z - q.z; a0 = fmaf(dx, dx, a0);
        dx = v0.w - q.w; a0 = fmaf(dx, dx, a0);
        dx = v1.x - q.x; a1 = fmaf(dx, dx, a1);
        dx = v1.y - q.y; a1 = fmaf(dx, dx, a1);
        dx = v1.z - q.z; a1 = fmaf(dx, dx, a1);
        dx = v1.w - q.w; a1 = fmaf(dx, dx, a1);
        dx = v2.x - q.x; a2 = fmaf(dx, dx, a2);
        dx = v2.y - q.y; a2 = fmaf(dx, dx, a2);
        dx = v2.z - q.z; a2 = fmaf(dx, dx, a2);
        dx = v2.w - q.w; a2 = fmaf(dx, dx, a2);
        dx = v3.x - q.x; a3 = fmaf(dx, dx, a3);
        dx = v3.y - q.y; a3 = fmaf(dx, dx, a3);
        dx = v3.z - q.z; a3 = fmaf(dx, dx, a3);
        dx = v3.w - q.w; a3 = fmaf(dx, dx, a3);
    }

    // wave argmin over 64 lanes (distinct codes; tie-break on lower index)
    float bv[4] = {a0, a1, a2, a3};
    int   bi[4] = {ci, ci, ci, ci};
    #pragma unroll
    for (int m = 1; m < 64; m <<= 1) {
        #pragma unroll
        for (int rr = 0; rr < 4; ++rr) {
            const float ov = __shfl_xor(bv[rr], m);
            const int   oi = __shfl_xor(bi[rr], m);
            if (ov < bv[rr] || (ov == bv[rr] && oi < bi[rr])) { bv[rr] = ov; bi[rr] = oi; }
        }
    }
    if (lane == 0) {
        #pragma unroll
        for (int rr = 0; rr < 4; ++rr) {
            red_v[(rg * 4 + rr) * 4 + cq] = bv[rr];
            red_i[(rg * 4 + rr) * 4 + cq] = bi[rr];
        }
    }
    __syncthreads();
    if (tid < RB) {   // merge the 4 code-quarter candidates per row (ascending cq)
        float v0 = red_v[tid * 4]; int i0 = red_i[tid * 4];
        #pragma unroll
        for (int k = 1; k < 4; ++k) {
            const float ov = red_v[tid * 4 + k];
            const int   oi = red_i[tid * 4 + k];
            if (ov < v0 || (ov == v0 && oi < i0)) { v0 = ov; i0 = oi; }
        }
        row_idx[tid] = i0;
        out[(size_t)BD * DD + row0 + tid] = (float)i0;
    }
    __syncthreads();

    // ---------- Phase C: quantized = R * codes[idx] (rank-2), + loss ----------
    // wave wv -> row wv; lane holds 2 elements; code row from LDS.
    {
        const int r = wv;
        const int qi = row_idx[r];
        const float invn = row_invn[r];
        const float c = row_c[r];
        const float s = row_s[r];
        const size_t grow = (size_t)(row0 + r);
        const float2 q = ((const float2*)(code_s + qi * SF))[lane];
        const float2 p = ((const float2*)(pq + grow * DD))[lane];
        float pd = p.x * q.x + p.y * q.y;
        float ws = q.x + q.y;
        #pragma unroll
        for (int m = 32; m > 0; m >>= 1) {
            pd += __shfl_xor(pd, m);
            ws += __shfl_xor(ws, m);
        }
        const float pp = pd * invn;          // u . q
        const float w  = ws * INV_SQRT_D;    // v . q
        // R q = q + u*(w + s(cw - p)) + v*(-p + s(cp - w))
        const float bu  =  w + s * (c * w - pp);
        const float bvv = -pp + s * (c * pp - w);
        float2 o;
        o.x = q.x + bu * (p.x * invn) + bvv * INV_SQRT_D;
        o.y = q.y + bu * (p.y * invn) + bvv * INV_SQRT_D;
        ((float2*)(out + grow * DD))[lane] = o;

        const float2 xv = ((const float2*)(x + grow * DD))[lane];
        float dx = xv.x - o.x;
        float ls = dx * dx;
        dx = xv.y - o.y;
        ls = fmaf(dx, dx, ls);
        #pragma unroll
        for (int m = 32; m > 0; m >>= 1) ls += __shfl_xor(ls, m);
        if (lane == 0) loss_s[r] = ls;
    }
    __syncthreads();
    if (tid == 0) {
        float tot = 0.f;
        #pragma unroll
        for (int r = 0; r < RB; ++r) tot += loss_s[r];
        // loss = loss_commit + 0.25*loss_codebook = 1.25 * mean_b ||x - q||^2
        atomicAdd(out + (size_t)BD * DD + BD, tot * (1.25f / (float)BD));
    }
}

extern "C" void kernel_launch(void* const* d_in, const int* in_sizes, int n_in,
                              void* d_out, int out_size, void* d_ws, size_t ws_size,
                              hipStream_t stream) {
    const float* xin   = (const float*)d_in[0];
    const float* prevq = (const float*)d_in[1];
    const float* codes = (const float*)d_in[2];
    float* out = (float*)d_out;
    // zero the loss accumulator slot (harness poisons d_out with 0xAA)
    hipMemsetAsync((void*)(out + (size_t)BD * DD + BD), 0, sizeof(float), stream);
    rq_fused<<<BD / RB, TB, 0, stream>>>(xin, prevq, codes, out);
}